// Round 1
// baseline (113.859 us; speedup 1.0000x reference)
//
#include <hip/hip_runtime.h>
#include <math.h>

#define H2 512
#define NB 64
#define TK 2048
#define SPLIT 16

#define LOG2E 1.44269504088896f
#define TWO_LOG2E 2.88539008177793f

// ---------------- K1: dec_fea = s_t_hat @ W_dp^T + b_dp  [NB, H2] ----------------
// grid (NB, 16), block 256 (4 waves). Each wave computes 8 consecutive n, one per iter.
__global__ __launch_bounds__(256) void k_decproj(const float* __restrict__ s,
                                                 const float* __restrict__ W,
                                                 const float* __restrict__ bias,
                                                 float* __restrict__ dec) {
    const int bb = blockIdx.x;
    const int wave = threadIdx.x >> 6;
    const int lane = threadIdx.x & 63;
    const float* srow = s + bb * H2;
    float4 s0 = *(const float4*)(srow + lane * 8);
    float4 s1 = *(const float4*)(srow + lane * 8 + 4);
    #pragma unroll
    for (int i = 0; i < 8; ++i) {
        const int n = blockIdx.y * 32 + wave * 8 + i;
        const float* wrow = W + (size_t)n * H2;
        float4 w0 = *(const float4*)(wrow + lane * 8);
        float4 w1 = *(const float4*)(wrow + lane * 8 + 4);
        float acc = s0.x * w0.x + s0.y * w0.y + s0.z * w0.z + s0.w * w0.w +
                    s1.x * w1.x + s1.y * w1.y + s1.z * w1.z + s1.w * w1.w;
        #pragma unroll
        for (int off = 1; off < 64; off <<= 1) acc += __shfl_xor(acc, off, 64);
        if (lane == 0) dec[bb * H2 + n] = acc + bias[n];
    }
}

// ---------------- K2: scores[b,t] = v_b + sum_n vw[n]*tanh(ef + dec + cov*wc) ----
// grid (TK/16, NB), block 256 (4 waves); one wave per t-row, lane owns 8 n.
// tanh(x) = 1 - 2*rcp(exp2(x*2log2e)+1); sum vw*tanh = sum(vw) + sum((-2vw)*rcp(...))
__global__ __launch_bounds__(256) void k_scores(const float* __restrict__ ef,
                                                const float* __restrict__ dec,
                                                const float* __restrict__ cov,
                                                const float* __restrict__ wc,
                                                const float* __restrict__ vw,
                                                const float* __restrict__ vbp,
                                                float* __restrict__ scores) {
    const int bb = blockIdx.y;
    const int wave = threadIdx.x >> 6;
    const int lane = threadIdx.x & 63;
    const int n0 = lane * 8;

    float4 d0 = *(const float4*)(dec + bb * H2 + n0);
    float4 d1 = *(const float4*)(dec + bb * H2 + n0 + 4);
    float4 c0 = *(const float4*)(wc + n0);
    float4 c1 = *(const float4*)(wc + n0 + 4);
    float4 v0 = *(const float4*)(vw + n0);
    float4 v1 = *(const float4*)(vw + n0 + 4);

    float vwsum = v0.x + v0.y + v0.z + v0.w + v1.x + v1.y + v1.z + v1.w;
    #pragma unroll
    for (int off = 1; off < 64; off <<= 1) vwsum += __shfl_xor(vwsum, off, 64);

    // pre-scale: acc term = (-2*vw) * rcp(exp2(att*2log2e)+1)
    v0.x *= -2.f; v0.y *= -2.f; v0.z *= -2.f; v0.w *= -2.f;
    v1.x *= -2.f; v1.y *= -2.f; v1.z *= -2.f; v1.w *= -2.f;
    const float vb = vbp[0];

    const int t0 = blockIdx.x * 16;
    for (int r = wave; r < 16; r += 4) {
        const int t = t0 + r;
        const size_t base = ((size_t)bb * TK + t) * H2;
        float4 e0 = *(const float4*)(ef + base + n0);
        float4 e1 = *(const float4*)(ef + base + n0 + 4);
        const float covt = cov[bb * TK + t];

        #define TERM(E, D, C, V) \
            ((V) * __builtin_amdgcn_rcpf(__builtin_amdgcn_exp2f(((E) + (D) + covt * (C)) * TWO_LOG2E) + 1.0f))
        float acc = TERM(e0.x, d0.x, c0.x, v0.x) + TERM(e0.y, d0.y, c0.y, v0.y) +
                    TERM(e0.z, d0.z, c0.z, v0.z) + TERM(e0.w, d0.w, c0.w, v0.w) +
                    TERM(e1.x, d1.x, c1.x, v1.x) + TERM(e1.y, d1.y, c1.y, v1.y) +
                    TERM(e1.z, d1.z, c1.z, v1.z) + TERM(e1.w, d1.w, c1.w, v1.w);
        #undef TERM

        #pragma unroll
        for (int off = 1; off < 64; off <<= 1) acc += __shfl_xor(acc, off, 64);
        if (lane == 0) scores[bb * TK + t] = vwsum + acc + vb;
    }
}

// ---------------- K3: softmax+mask renorm (in-place on scores==attn slot) --------
// attn = e*mask/sum(e*mask);  coverage_new = cov + attn.  grid NB, block 256.
__global__ __launch_bounds__(256) void k_softmax(float* __restrict__ attn,
                                                 const float* __restrict__ mask,
                                                 const float* __restrict__ cov,
                                                 float* __restrict__ covnew) {
    const int bb = blockIdx.x;
    const int tid = threadIdx.x;
    const int lane = tid & 63, wave = tid >> 6;
    float s[8], mk[8];
    float m = -1e30f;
    #pragma unroll
    for (int i = 0; i < 8; ++i) {
        const int t = tid + i * 256;
        s[i] = attn[bb * TK + t];
        mk[i] = mask[bb * TK + t];
        m = fmaxf(m, s[i]);
    }
    #pragma unroll
    for (int off = 1; off < 64; off <<= 1) m = fmaxf(m, __shfl_xor(m, off, 64));
    __shared__ float redm[4], reds[4];
    if (lane == 0) redm[wave] = m;
    __syncthreads();
    m = fmaxf(fmaxf(redm[0], redm[1]), fmaxf(redm[2], redm[3]));

    float e[8];
    float sum = 0.f;
    #pragma unroll
    for (int i = 0; i < 8; ++i) {
        e[i] = __builtin_amdgcn_exp2f((s[i] - m) * LOG2E) * mk[i];
        sum += e[i];
    }
    #pragma unroll
    for (int off = 1; off < 64; off <<= 1) sum += __shfl_xor(sum, off, 64);
    if (lane == 0) reds[wave] = sum;
    __syncthreads();
    sum = reds[0] + reds[1] + reds[2] + reds[3];
    const float inv = 1.0f / sum;

    #pragma unroll
    for (int i = 0; i < 8; ++i) {
        const int t = tid + i * 256;
        const float a = e[i] * inv;
        attn[bb * TK + t] = a;
        covnew[bb * TK + t] = cov[bb * TK + t] + a;
    }
}

// ---------------- K4: partial c_t = sum_t attn * encoder_outputs ------------------
// grid (SPLIT, NB), block 256: 128 n-groups (float4) x 2 t-lanes.
__global__ __launch_bounds__(256) void k_ct_part(const float* __restrict__ eo,
                                                 const float* __restrict__ attn,
                                                 float* __restrict__ part) {
    const int bb = blockIdx.y, sp = blockIdx.x;
    const int tid = threadIdx.x;
    const int ng = tid & 127, th = tid >> 7;
    const int t0 = sp * (TK / SPLIT);
    float4 acc = make_float4(0.f, 0.f, 0.f, 0.f);
    for (int t = t0 + th; t < t0 + (TK / SPLIT); t += 2) {
        const float a = attn[bb * TK + t];
        const float4 v = *((const float4*)(eo + ((size_t)bb * TK + t) * H2) + ng);
        acc.x += a * v.x; acc.y += a * v.y; acc.z += a * v.z; acc.w += a * v.w;
    }
    __shared__ float4 lds[128];
    if (th) lds[ng] = acc;
    __syncthreads();
    if (!th) {
        const float4 o = lds[ng];
        acc.x += o.x; acc.y += o.y; acc.z += o.z; acc.w += o.w;
        *(float4*)(part + ((size_t)(bb * SPLIT + sp)) * H2 + ng * 4) = acc;
    }
}

// ---------------- K5: finalize c_t ------------------------------------------------
__global__ __launch_bounds__(512) void k_ct_final(const float* __restrict__ part,
                                                  float* __restrict__ ct) {
    const int bb = blockIdx.x, n = threadIdx.x;
    float acc = 0.f;
    #pragma unroll
    for (int sp = 0; sp < SPLIT; ++sp) acc += part[((size_t)(bb * SPLIT + sp)) * H2 + n];
    ct[bb * H2 + n] = acc;
}

extern "C" void kernel_launch(void* const* d_in, const int* in_sizes, int n_in,
                              void* d_out, int out_size, void* d_ws, size_t ws_size,
                              hipStream_t stream) {
    const float* s_t_hat  = (const float*)d_in[0];
    const float* enc_out  = (const float*)d_in[1];
    const float* enc_feat = (const float*)d_in[2];
    const float* mask     = (const float*)d_in[3];
    const float* cov      = (const float*)d_in[4];
    const float* W_dp     = (const float*)d_in[5];
    const float* b_dp     = (const float*)d_in[6];
    const float* W_c      = (const float*)d_in[7];
    const float* v_w      = (const float*)d_in[8];
    const float* v_b      = (const float*)d_in[9];

    float* out = (float*)d_out;
    float* ct     = out;                       // [NB, H2]      32768
    float* attn   = out + NB * H2;             // [NB, TK]      131072 (scores staged here)
    float* covnew = attn + NB * TK;            // [NB, TK]      131072

    float* dec  = (float*)d_ws;                // [NB, H2]           128 KB
    float* part = dec + NB * H2;               // [NB, SPLIT, H2]    2 MB

    k_decproj<<<dim3(NB, 16), 256, 0, stream>>>(s_t_hat, W_dp, b_dp, dec);
    k_scores<<<dim3(TK / 16, NB), 256, 0, stream>>>(enc_feat, dec, cov, W_c, v_w, v_b, attn);
    k_softmax<<<NB, 256, 0, stream>>>(attn, mask, cov, covnew);
    k_ct_part<<<dim3(SPLIT, NB), 256, 0, stream>>>(enc_out, attn, part);
    k_ct_final<<<NB, 512, 0, stream>>>(part, ct);
}